// Round 1
// baseline (369.597 us; speedup 1.0000x reference)
//
#include <hip/hip_runtime.h>
#include <hip/hip_bf16.h>
#include <math.h>

#define B_  32
#define L_  256
#define F_  20
#define H_  256
#define DI_ 512
#define N_  64
#define R_  16
#define KC_ 4

// ---------------------------------------------------------------------------
// Generic fp32 GEMM (NT): C[m,n] = sum_k A[m*lda+k] * W[n*ldw+k] (+bias[n])
// ACT: 0 = none, 1 = softplus
// ---------------------------------------------------------------------------
#define BM  64
#define BN  64
#define BKT 16

template<int ACT>
__global__ __launch_bounds__(256) void gemm_nt(
    const float* __restrict__ A, int lda,
    const float* __restrict__ W, int ldw,
    const float* __restrict__ bias,
    float* __restrict__ C, int ldc,
    int M, int N, int K)
{
    __shared__ float As[BKT][BM + 4];
    __shared__ float Bs[BKT][BN + 4];
    const int tid = threadIdx.x;
    const int tx = tid & 15, ty = tid >> 4;
    const int m0 = blockIdx.y * BM;
    const int n0 = blockIdx.x * BN;
    float c[4][4] = {};

    for (int k0 = 0; k0 < K; k0 += BKT) {
#pragma unroll
        for (int i = 0; i < 4; i++) {
            int idx = tid + i * 256;
            int row = idx >> 4, kk = idx & 15;
            int m = m0 + row, k = k0 + kk;
            As[kk][row] = (m < M && k < K) ? A[(size_t)m * lda + k] : 0.f;
            int n = n0 + row;
            Bs[kk][row] = (n < N && k < K) ? W[(size_t)n * ldw + k] : 0.f;
        }
        __syncthreads();
#pragma unroll
        for (int kk = 0; kk < BKT; kk++) {
            float a[4], bb[4];
#pragma unroll
            for (int i = 0; i < 4; i++) a[i] = As[kk][ty * 4 + i];
#pragma unroll
            for (int j = 0; j < 4; j++) bb[j] = Bs[kk][tx * 4 + j];
#pragma unroll
            for (int i = 0; i < 4; i++)
#pragma unroll
                for (int j = 0; j < 4; j++)
                    c[i][j] = fmaf(a[i], bb[j], c[i][j]);
        }
        __syncthreads();
    }

#pragma unroll
    for (int i = 0; i < 4; i++) {
        int m = m0 + ty * 4 + i;
        if (m >= M) continue;
#pragma unroll
        for (int j = 0; j < 4; j++) {
            int n = n0 + tx * 4 + j;
            if (n >= N) continue;
            float v = c[i][j];
            if (bias) v += bias[n];
            if (ACT == 1) v = (v > 20.f) ? v : log1pf(__expf(v));
            C[(size_t)m * ldc + n] = v;
        }
    }
}

// ---------------------------------------------------------------------------
// Depthwise causal conv (K=4) + SiLU.  u layout (b, t, d), d contiguous.
// ---------------------------------------------------------------------------
__global__ __launch_bounds__(256) void conv_silu_kernel(
    const float* __restrict__ u_pre,
    const float* __restrict__ conv_w,
    const float* __restrict__ conv_b,
    float* __restrict__ u)
{
    int id = blockIdx.x * 256 + threadIdx.x;
    if (id >= B_ * L_ * DI_) return;
    int d  = id % DI_;
    int bl = id / DI_;
    int t  = bl % L_;
    int b  = bl / L_;
    float acc = conv_b[d];
#pragma unroll
    for (int k = 0; k < KC_; k++) {
        int tt = t + k - (KC_ - 1);
        if (tt >= 0)
            acc = fmaf(u_pre[((size_t)(b * L_ + tt)) * DI_ + d], conv_w[d * KC_ + k], acc);
    }
    float s = 1.f / (1.f + __expf(-acc));
    u[id] = acc * s;
}

// ---------------------------------------------------------------------------
// Selective scan. One wave (64 lanes = n) per (b, d0..d0+7).
// h_t = exp(delta*A[d,n])*h_{t-1} + (delta*u)*B_t[n];  y only at t=L-1.
// ---------------------------------------------------------------------------
#define DPER 8
__global__ __launch_bounds__(64) void scan_kernel(
    const float* __restrict__ delta,
    const float* __restrict__ u,
    const float* __restrict__ dbc,     // (B*L, 144): [0:16)=dt, [16:80)=B, [80:144)=C
    const float* __restrict__ A_log,
    const float* __restrict__ Dv,
    float* __restrict__ y_last)        // (B, DI)
{
    const int lane = threadIdx.x;
    const int blk  = blockIdx.x;
    const int b    = blk >> 6;               // DI_/DPER = 64 blocks per batch
    const int d0   = (blk & 63) * DPER;

    float Arow[DPER], hs[DPER];
#pragma unroll
    for (int j = 0; j < DPER; j++) {
        Arow[j] = -__expf(A_log[(size_t)(d0 + j) * N_ + lane]);
        hs[j] = 0.f;
    }

    const size_t rowB = (size_t)b * L_;
    for (int t = 0; t < L_; t++) {
        const float Bt = dbc[(rowB + t) * 144 + R_ + lane];
        const float* dl = delta + (rowB + t) * DI_ + d0;
        const float* ul = u     + (rowB + t) * DI_ + d0;
#pragma unroll
        for (int j = 0; j < DPER; j++) {
            float dv  = dl[j];
            float duv = dv * ul[j];
            hs[j] = fmaf(__expf(dv * Arow[j]), hs[j], duv * Bt);
        }
    }

    const float Ct = dbc[(rowB + L_ - 1) * 144 + R_ + N_ + lane];
    const float* ulast = u + (rowB + L_ - 1) * DI_ + d0;
#pragma unroll
    for (int j = 0; j < DPER; j++) {
        float v = hs[j] * Ct;
#pragma unroll
        for (int m = 32; m > 0; m >>= 1) v += __shfl_xor(v, m, 64);
        if (lane == 0)
            y_last[b * DI_ + d0 + j] = v + ulast[j] * Dv[d0 + j];
    }
}

// ---------------------------------------------------------------------------
// Final: gate, out_proj, fc1+relu, fc2, softmax.  One block per batch row.
// ---------------------------------------------------------------------------
__global__ __launch_bounds__(256) void final_kernel(
    const float* __restrict__ y_last, const float* __restrict__ z_last,
    const float* __restrict__ out_w,  const float* __restrict__ out_b,
    const float* __restrict__ fc1_w,  const float* __restrict__ fc1_b,
    const float* __restrict__ fc2_w,  const float* __restrict__ fc2_b,
    float* __restrict__ out)
{
    __shared__ float yz[DI_];
    __shared__ float feat[H_];
    __shared__ float h1[64];
    __shared__ float lg[2];
    const int b = blockIdx.x, tid = threadIdx.x;

    for (int d = tid; d < DI_; d += 256) {
        float z = z_last[b * DI_ + d];
        float s = 1.f / (1.f + __expf(-z));
        yz[d] = y_last[b * DI_ + d] * z * s;
    }
    __syncthreads();

    {
        float acc = out_b[tid];
        const float* wr = out_w + (size_t)tid * DI_;
        for (int d = 0; d < DI_; d++) acc = fmaf(yz[d], wr[d], acc);
        feat[tid] = acc;
    }
    __syncthreads();

    if (tid < 64) {
        float acc = fc1_b[tid];
        const float* wr = fc1_w + tid * H_;
        for (int hh = 0; hh < H_; hh++) acc = fmaf(feat[hh], wr[hh], acc);
        h1[tid] = acc > 0.f ? acc : 0.f;
    }
    __syncthreads();

    if (tid < 2) {
        float acc = fc2_b[tid];
        const float* wr = fc2_w + tid * 64;
        for (int j = 0; j < 64; j++) acc = fmaf(h1[j], wr[j], acc);
        lg[tid] = acc;
    }
    __syncthreads();

    if (tid == 0) {
        float m = fmaxf(lg[0], lg[1]);
        float e0 = __expf(lg[0] - m), e1 = __expf(lg[1] - m);
        float s = e0 + e1;
        out[b * 2 + 0] = e0 / s;
        out[b * 2 + 1] = e1 / s;
    }
}

// ---------------------------------------------------------------------------
extern "C" void kernel_launch(void* const* d_in, const int* in_sizes, int n_in,
                              void* d_out, int out_size, void* d_ws, size_t ws_size,
                              hipStream_t stream)
{
    const float* x         = (const float*)d_in[0];
    const float* emb_w     = (const float*)d_in[1];
    const float* emb_b     = (const float*)d_in[2];
    const float* in_proj_w = (const float*)d_in[3];
    const float* in_proj_b = (const float*)d_in[4];
    const float* conv_w    = (const float*)d_in[5];
    const float* conv_b    = (const float*)d_in[6];
    const float* x_proj_w  = (const float*)d_in[7];
    const float* dt_proj_w = (const float*)d_in[8];
    const float* dt_proj_b = (const float*)d_in[9];
    const float* A_log     = (const float*)d_in[10];
    const float* Dv        = (const float*)d_in[11];
    const float* out_w     = (const float*)d_in[12];
    const float* out_b     = (const float*)d_in[13];
    const float* fc1_w     = (const float*)d_in[14];
    const float* fc1_b     = (const float*)d_in[15];
    const float* fc2_w     = (const float*)d_in[16];
    const float* fc2_b     = (const float*)d_in[17];
    float* out = (float*)d_out;

    // workspace layout (floats)
    float* ws    = (float*)d_ws;
    float* hbuf  = ws;                      // 8192*256   = 2,097,152
    float* u_pre = hbuf  + 2097152;         // 8192*512   = 4,194,304
    float* ubuf  = u_pre + 4194304;         // 8192*512   = 4,194,304
    float* dbc   = ubuf  + 4194304;         // 8192*144   = 1,179,648
    float* delta = dbc   + 1179648;         // 8192*512   = 4,194,304
    float* zlast = delta + 4194304;         // 32*512
    float* ylast = zlast + B_ * DI_;        // 32*512

    dim3 blk(256);
    const int MBL = B_ * L_;  // 8192

    // 1. emb: h = x @ emb_w^T + emb_b           (8192,20)x(256,20)
    gemm_nt<0><<<dim3(H_ / BN, MBL / BM), blk, 0, stream>>>(
        x, F_, emb_w, F_, emb_b, hbuf, H_, MBL, H_, F_);

    // 2. in_proj (u half): u_pre = h @ Wu^T + bu (8192,256)x(512,256)
    gemm_nt<0><<<dim3(DI_ / BN, MBL / BM), blk, 0, stream>>>(
        hbuf, H_, in_proj_w, H_, in_proj_b, u_pre, DI_, MBL, DI_, H_);

    // 3. z at t = L-1 only: (32,256)x(512,256)
    gemm_nt<0><<<dim3(DI_ / BN, 1), blk, 0, stream>>>(
        hbuf + (L_ - 1) * H_, L_ * H_, in_proj_w + DI_ * H_, H_,
        in_proj_b + DI_, zlast, DI_, B_, DI_, H_);

    // 4. depthwise conv + SiLU
    conv_silu_kernel<<<(B_ * L_ * DI_) / 256, blk, 0, stream>>>(
        u_pre, conv_w, conv_b, ubuf);

    // 5. x_proj: dbc = u @ x_proj_w^T           (8192,512)x(144,512)
    gemm_nt<0><<<dim3(3, MBL / BM), blk, 0, stream>>>(
        ubuf, DI_, x_proj_w, DI_, nullptr, dbc, 144, MBL, 144, DI_);

    // 6. dt_proj + softplus: delta              (8192,16)x(512,16)
    gemm_nt<1><<<dim3(DI_ / BN, MBL / BM), blk, 0, stream>>>(
        dbc, 144, dt_proj_w, R_, dt_proj_b, delta, DI_, MBL, DI_, R_);

    // 7. selective scan (y only at last t)
    scan_kernel<<<B_ * (DI_ / DPER), dim3(64), 0, stream>>>(
        delta, ubuf, dbc, A_log, Dv, ylast);

    // 8. gate + out_proj + fc1 + fc2 + softmax
    final_kernel<<<B_, blk, 0, stream>>>(
        ylast, zlast, out_w, out_b, fc1_w, fc1_b, fc2_w, fc2_b, out);
}

// Round 2
// 351.116 us; speedup vs baseline: 1.0526x; 1.0526x over previous
//
#include <hip/hip_runtime.h>
#include <hip/hip_bf16.h>
#include <math.h>

#define B_  32
#define L_  256
#define F_  20
#define H_  256
#define DI_ 512
#define N_  64
#define R_  16
#define KC_ 4

// ---------------------------------------------------------------------------
// Generic fp32 GEMM (NT): C[m,n] = sum_k A[m*lda+k] * W[n*ldw+k] (+bias[n])
// ACT: 0 = none, 1 = softplus
// ---------------------------------------------------------------------------
#define BM  64
#define BN  64
#define BKT 16

template<int ACT>
__global__ __launch_bounds__(256) void gemm_nt(
    const float* __restrict__ A, int lda,
    const float* __restrict__ W, int ldw,
    const float* __restrict__ bias,
    float* __restrict__ C, int ldc,
    int M, int N, int K)
{
    __shared__ float As[BKT][BM + 4];
    __shared__ float Bs[BKT][BN + 4];
    const int tid = threadIdx.x;
    const int tx = tid & 15, ty = tid >> 4;
    const int m0 = blockIdx.y * BM;
    const int n0 = blockIdx.x * BN;
    float c[4][4] = {};

    for (int k0 = 0; k0 < K; k0 += BKT) {
#pragma unroll
        for (int i = 0; i < 4; i++) {
            int idx = tid + i * 256;
            int row = idx >> 4, kk = idx & 15;
            int m = m0 + row, k = k0 + kk;
            As[kk][row] = (m < M && k < K) ? A[(size_t)m * lda + k] : 0.f;
            int n = n0 + row;
            Bs[kk][row] = (n < N && k < K) ? W[(size_t)n * ldw + k] : 0.f;
        }
        __syncthreads();
#pragma unroll
        for (int kk = 0; kk < BKT; kk++) {
            // vectorized LDS reads: 2x ds_read_b128 instead of 8x ds_read_b32
            const float4 av = *(const float4*)&As[kk][ty * 4];
            const float4 bv = *(const float4*)&Bs[kk][tx * 4];
            const float a0 = av.x, a1 = av.y, a2 = av.z, a3 = av.w;
            const float b0 = bv.x, b1 = bv.y, b2 = bv.z, b3 = bv.w;
            c[0][0] = fmaf(a0, b0, c[0][0]); c[0][1] = fmaf(a0, b1, c[0][1]);
            c[0][2] = fmaf(a0, b2, c[0][2]); c[0][3] = fmaf(a0, b3, c[0][3]);
            c[1][0] = fmaf(a1, b0, c[1][0]); c[1][1] = fmaf(a1, b1, c[1][1]);
            c[1][2] = fmaf(a1, b2, c[1][2]); c[1][3] = fmaf(a1, b3, c[1][3]);
            c[2][0] = fmaf(a2, b0, c[2][0]); c[2][1] = fmaf(a2, b1, c[2][1]);
            c[2][2] = fmaf(a2, b2, c[2][2]); c[2][3] = fmaf(a2, b3, c[2][3]);
            c[3][0] = fmaf(a3, b0, c[3][0]); c[3][1] = fmaf(a3, b1, c[3][1]);
            c[3][2] = fmaf(a3, b2, c[3][2]); c[3][3] = fmaf(a3, b3, c[3][3]);
        }
        __syncthreads();
    }

#pragma unroll
    for (int i = 0; i < 4; i++) {
        int m = m0 + ty * 4 + i;
        if (m >= M) continue;
#pragma unroll
        for (int j = 0; j < 4; j++) {
            int n = n0 + tx * 4 + j;
            if (n >= N) continue;
            float v = c[i][j];
            if (bias) v += bias[n];
            if (ACT == 1) v = (v > 20.f) ? v : log1pf(__expf(v));
            C[(size_t)m * ldc + n] = v;
        }
    }
}

// ---------------------------------------------------------------------------
// Depthwise causal conv (K=4) + SiLU.  u layout (b, t, d), d contiguous.
// ---------------------------------------------------------------------------
__global__ __launch_bounds__(256) void conv_silu_kernel(
    const float* __restrict__ u_pre,
    const float* __restrict__ conv_w,
    const float* __restrict__ conv_b,
    float* __restrict__ u)
{
    int id = blockIdx.x * 256 + threadIdx.x;
    if (id >= B_ * L_ * DI_) return;
    int d  = id % DI_;
    int bl = id / DI_;
    int t  = bl % L_;
    int b  = bl / L_;
    float acc = conv_b[d];
#pragma unroll
    for (int k = 0; k < KC_; k++) {
        int tt = t + k - (KC_ - 1);
        if (tt >= 0)
            acc = fmaf(u_pre[((size_t)(b * L_ + tt)) * DI_ + d], conv_w[d * KC_ + k], acc);
    }
    float s = 1.f / (1.f + __expf(-acc));
    u[id] = acc * s;
}

// ---------------------------------------------------------------------------
// Selective scan. One wave per (b, 4 d's), lane = n.  16 waves/CU occupancy.
// Register double-buffer: prefetch t+1 while computing t.
// h_t = exp(delta*A[d,n])*h_{t-1} + (delta*u)*B_t[n];  y only at t=L-1.
// ---------------------------------------------------------------------------
#define DPER 4
__global__ __launch_bounds__(64) void scan_kernel(
    const float* __restrict__ delta,
    const float* __restrict__ u,
    const float* __restrict__ dbc,     // (B*L, 144): [0:16)=dt, [16:80)=B, [80:144)=C
    const float* __restrict__ A_log,
    const float* __restrict__ Dv,
    float* __restrict__ y_last)        // (B, DI)
{
    const int lane = threadIdx.x;
    const int blk  = blockIdx.x;
    const int b    = blk >> 7;               // DI_/DPER = 128 blocks per batch
    const int d0   = (blk & 127) * DPER;

    float Arow[DPER], hs[DPER];
#pragma unroll
    for (int j = 0; j < DPER; j++) {
        Arow[j] = -__expf(A_log[(size_t)(d0 + j) * N_ + lane]);
        hs[j] = 0.f;
    }

    const size_t rowBase = (size_t)b * L_;
    const float* dptr = delta + rowBase * DI_ + d0;
    const float* uptr = u     + rowBase * DI_ + d0;
    const float* bptr = dbc   + rowBase * 144 + R_ + lane;

    float4 dv = *(const float4*)dptr;
    float4 uv = *(const float4*)uptr;
    float  Bt = *bptr;

    for (int t = 0; t < L_; t++) {
        const int tn = (t + 1 < L_) ? t + 1 : t;   // branch-free prefetch index
        const float4 dn = *(const float4*)(dptr + (size_t)tn * DI_);
        const float4 un = *(const float4*)(uptr + (size_t)tn * DI_);
        const float  Bn = bptr[(size_t)tn * 144];

#define SSTEP(j, DD, UU) { \
        float e = __expf((DD) * Arow[j]); \
        hs[j] = fmaf(e, hs[j], (DD) * (UU) * Bt); }
        SSTEP(0, dv.x, uv.x)
        SSTEP(1, dv.y, uv.y)
        SSTEP(2, dv.z, uv.z)
        SSTEP(3, dv.w, uv.w)
#undef SSTEP

        dv = dn; uv = un; Bt = Bn;
    }

    const float Ct = dbc[(rowBase + L_ - 1) * 144 + R_ + N_ + lane];
    const float* ulast = u + (rowBase + L_ - 1) * DI_ + d0;
#pragma unroll
    for (int j = 0; j < DPER; j++) {
        float v = hs[j] * Ct;
#pragma unroll
        for (int m = 32; m > 0; m >>= 1) v += __shfl_xor(v, m, 64);
        if (lane == 0)
            y_last[b * DI_ + d0 + j] = v + ulast[j] * Dv[d0 + j];
    }
}

// ---------------------------------------------------------------------------
// Final: gate, out_proj, fc1+relu, fc2, softmax.  One block per batch row.
// ---------------------------------------------------------------------------
__global__ __launch_bounds__(256) void final_kernel(
    const float* __restrict__ y_last, const float* __restrict__ z_last,
    const float* __restrict__ out_w,  const float* __restrict__ out_b,
    const float* __restrict__ fc1_w,  const float* __restrict__ fc1_b,
    const float* __restrict__ fc2_w,  const float* __restrict__ fc2_b,
    float* __restrict__ out)
{
    __shared__ float yz[DI_];
    __shared__ float feat[H_];
    __shared__ float h1[64];
    __shared__ float lg[2];
    const int b = blockIdx.x, tid = threadIdx.x;

    for (int d = tid; d < DI_; d += 256) {
        float z = z_last[b * DI_ + d];
        float s = 1.f / (1.f + __expf(-z));
        yz[d] = y_last[b * DI_ + d] * z * s;
    }
    __syncthreads();

    {
        float acc = out_b[tid];
        const float* wr = out_w + (size_t)tid * DI_;
        for (int d = 0; d < DI_; d++) acc = fmaf(yz[d], wr[d], acc);
        feat[tid] = acc;
    }
    __syncthreads();

    if (tid < 64) {
        float acc = fc1_b[tid];
        const float* wr = fc1_w + tid * H_;
        for (int hh = 0; hh < H_; hh++) acc = fmaf(feat[hh], wr[hh], acc);
        h1[tid] = acc > 0.f ? acc : 0.f;
    }
    __syncthreads();

    if (tid < 2) {
        float acc = fc2_b[tid];
        const float* wr = fc2_w + tid * 64;
        for (int j = 0; j < 64; j++) acc = fmaf(h1[j], wr[j], acc);
        lg[tid] = acc;
    }
    __syncthreads();

    if (tid == 0) {
        float m = fmaxf(lg[0], lg[1]);
        float e0 = __expf(lg[0] - m), e1 = __expf(lg[1] - m);
        float s = e0 + e1;
        out[b * 2 + 0] = e0 / s;
        out[b * 2 + 1] = e1 / s;
    }
}

// ---------------------------------------------------------------------------
extern "C" void kernel_launch(void* const* d_in, const int* in_sizes, int n_in,
                              void* d_out, int out_size, void* d_ws, size_t ws_size,
                              hipStream_t stream)
{
    const float* x         = (const float*)d_in[0];
    const float* emb_w     = (const float*)d_in[1];
    const float* emb_b     = (const float*)d_in[2];
    const float* in_proj_w = (const float*)d_in[3];
    const float* in_proj_b = (const float*)d_in[4];
    const float* conv_w    = (const float*)d_in[5];
    const float* conv_b    = (const float*)d_in[6];
    const float* x_proj_w  = (const float*)d_in[7];
    const float* dt_proj_w = (const float*)d_in[8];
    const float* dt_proj_b = (const float*)d_in[9];
    const float* A_log     = (const float*)d_in[10];
    const float* Dv        = (const float*)d_in[11];
    const float* out_w     = (const float*)d_in[12];
    const float* out_b     = (const float*)d_in[13];
    const float* fc1_w     = (const float*)d_in[14];
    const float* fc1_b     = (const float*)d_in[15];
    const float* fc2_w     = (const float*)d_in[16];
    const float* fc2_b     = (const float*)d_in[17];
    float* out = (float*)d_out;

    // workspace layout (floats)
    float* ws    = (float*)d_ws;
    float* hbuf  = ws;                      // 8192*256   = 2,097,152
    float* u_pre = hbuf  + 2097152;         // 8192*512   = 4,194,304
    float* ubuf  = u_pre + 4194304;         // 8192*512   = 4,194,304
    float* dbc   = ubuf  + 4194304;         // 8192*144   = 1,179,648
    float* delta = dbc   + 1179648;         // 8192*512   = 4,194,304
    float* zlast = delta + 4194304;         // 32*512
    float* ylast = zlast + B_ * DI_;        // 32*512

    dim3 blk(256);
    const int MBL = B_ * L_;  // 8192

    // 1. emb: h = x @ emb_w^T + emb_b           (8192,20)x(256,20)
    gemm_nt<0><<<dim3(H_ / BN, MBL / BM), blk, 0, stream>>>(
        x, F_, emb_w, F_, emb_b, hbuf, H_, MBL, H_, F_);

    // 2. in_proj (u half): u_pre = h @ Wu^T + bu (8192,256)x(512,256)
    gemm_nt<0><<<dim3(DI_ / BN, MBL / BM), blk, 0, stream>>>(
        hbuf, H_, in_proj_w, H_, in_proj_b, u_pre, DI_, MBL, DI_, H_);

    // 3. z at t = L-1 only: (32,256)x(512,256)
    gemm_nt<0><<<dim3(DI_ / BN, 1), blk, 0, stream>>>(
        hbuf + (L_ - 1) * H_, L_ * H_, in_proj_w + DI_ * H_, H_,
        in_proj_b + DI_, zlast, DI_, B_, DI_, H_);

    // 4. depthwise conv + SiLU
    conv_silu_kernel<<<(B_ * L_ * DI_) / 256, blk, 0, stream>>>(
        u_pre, conv_w, conv_b, ubuf);

    // 5. x_proj: dbc = u @ x_proj_w^T           (8192,512)x(144,512)
    gemm_nt<0><<<dim3(3, MBL / BM), blk, 0, stream>>>(
        ubuf, DI_, x_proj_w, DI_, nullptr, dbc, 144, MBL, 144, DI_);

    // 6. dt_proj + softplus: delta              (8192,16)x(512,16)
    gemm_nt<1><<<dim3(DI_ / BN, MBL / BM), blk, 0, stream>>>(
        dbc, 144, dt_proj_w, R_, dt_proj_b, delta, DI_, MBL, DI_, R_);

    // 7. selective scan (y only at last t)
    scan_kernel<<<B_ * (DI_ / DPER), dim3(64), 0, stream>>>(
        delta, ubuf, dbc, A_log, Dv, ylast);

    // 8. gate + out_proj + fc1 + fc2 + softmax
    final_kernel<<<B_, blk, 0, stream>>>(
        ylast, zlast, out_w, out_b, fc1_w, fc1_b, fc2_w, fc2_b, out);
}

// Round 3
// 305.442 us; speedup vs baseline: 1.2100x; 1.1495x over previous
//
#include <hip/hip_runtime.h>
#include <hip/hip_bf16.h>
#include <math.h>

#define B_  32
#define L_  256
#define F_  20
#define H_  256
#define DI_ 512
#define N_  64
#define R_  16
#define KC_ 4

// ---------------------------------------------------------------------------
// Generic fp32 GEMM (NT): C[m,n] = sum_k A[m*lda+k] * W[n*ldw+k] (+bias[n])
// ACT: 0 = none, 1 = softplus
// ---------------------------------------------------------------------------
#define BM  64
#define BN  64
#define BKT 16

template<int ACT>
__global__ __launch_bounds__(256) void gemm_nt(
    const float* __restrict__ A, int lda,
    const float* __restrict__ W, int ldw,
    const float* __restrict__ bias,
    float* __restrict__ C, int ldc,
    int M, int N, int K)
{
    __shared__ float As[BKT][BM + 4];
    __shared__ float Bs[BKT][BN + 4];
    const int tid = threadIdx.x;
    const int tx = tid & 15, ty = tid >> 4;
    const int m0 = blockIdx.y * BM;
    const int n0 = blockIdx.x * BN;
    float c[4][4] = {};

    for (int k0 = 0; k0 < K; k0 += BKT) {
#pragma unroll
        for (int i = 0; i < 4; i++) {
            int idx = tid + i * 256;
            int row = idx >> 4, kk = idx & 15;
            int m = m0 + row, k = k0 + kk;
            As[kk][row] = (m < M && k < K) ? A[(size_t)m * lda + k] : 0.f;
            int n = n0 + row;
            Bs[kk][row] = (n < N && k < K) ? W[(size_t)n * ldw + k] : 0.f;
        }
        __syncthreads();
#pragma unroll
        for (int kk = 0; kk < BKT; kk++) {
            const float4 av = *(const float4*)&As[kk][ty * 4];
            const float4 bv = *(const float4*)&Bs[kk][tx * 4];
            const float a0 = av.x, a1 = av.y, a2 = av.z, a3 = av.w;
            const float b0 = bv.x, b1 = bv.y, b2 = bv.z, b3 = bv.w;
            c[0][0] = fmaf(a0, b0, c[0][0]); c[0][1] = fmaf(a0, b1, c[0][1]);
            c[0][2] = fmaf(a0, b2, c[0][2]); c[0][3] = fmaf(a0, b3, c[0][3]);
            c[1][0] = fmaf(a1, b0, c[1][0]); c[1][1] = fmaf(a1, b1, c[1][1]);
            c[1][2] = fmaf(a1, b2, c[1][2]); c[1][3] = fmaf(a1, b3, c[1][3]);
            c[2][0] = fmaf(a2, b0, c[2][0]); c[2][1] = fmaf(a2, b1, c[2][1]);
            c[2][2] = fmaf(a2, b2, c[2][2]); c[2][3] = fmaf(a2, b3, c[2][3]);
            c[3][0] = fmaf(a3, b0, c[3][0]); c[3][1] = fmaf(a3, b1, c[3][1]);
            c[3][2] = fmaf(a3, b2, c[3][2]); c[3][3] = fmaf(a3, b3, c[3][3]);
        }
        __syncthreads();
    }

#pragma unroll
    for (int i = 0; i < 4; i++) {
        int m = m0 + ty * 4 + i;
        if (m >= M) continue;
#pragma unroll
        for (int j = 0; j < 4; j++) {
            int n = n0 + tx * 4 + j;
            if (n >= N) continue;
            float v = c[i][j];
            if (bias) v += bias[n];
            if (ACT == 1) v = (v > 20.f) ? v : log1pf(__expf(v));
            C[(size_t)m * ldc + n] = v;
        }
    }
}

// ---------------------------------------------------------------------------
// Depthwise causal conv (K=4) + SiLU.  u layout (b, t, d), d contiguous.
// ---------------------------------------------------------------------------
__global__ __launch_bounds__(256) void conv_silu_kernel(
    const float* __restrict__ u_pre,
    const float* __restrict__ conv_w,
    const float* __restrict__ conv_b,
    float* __restrict__ u)
{
    int id = blockIdx.x * 256 + threadIdx.x;
    if (id >= B_ * L_ * DI_) return;
    int d  = id % DI_;
    int bl = id / DI_;
    int t  = bl % L_;
    int b  = bl / L_;
    float acc = conv_b[d];
#pragma unroll
    for (int k = 0; k < KC_; k++) {
        int tt = t + k - (KC_ - 1);
        if (tt >= 0)
            acc = fmaf(u_pre[((size_t)(b * L_ + tt)) * DI_ + d], conv_w[d * KC_ + k], acc);
    }
    float s = 1.f / (1.f + __expf(-acc));
    u[id] = acc * s;
}

// ---------------------------------------------------------------------------
// Chunked selective scan, fully fused per (b, 8-d group) block.
// h_t = exp(delta*A)*h + (delta*u)*B_t is chunk-composable:
//   chunk transfer  h_out = exp(A * sum(delta)) * h_in + c_chunk
// Block = 4 waves; wave w scans chunks {w, w+4} (32 steps each, h0=0),
// results to LDS; then waves combine 8 chunks serially (8 exp+fma) and
// contract with C_{L-1}.  Lane = n.
// ---------------------------------------------------------------------------
#define DPER 8
#define NCH  8
#define CHT  32   // L_/NCH

__global__ __launch_bounds__(256) void scan_chunk_kernel(
    const float* __restrict__ delta,
    const float* __restrict__ u,
    const float* __restrict__ dbc,     // (B*L,144): [0:16)=dt [16:80)=B [80:144)=C
    const float* __restrict__ A_log,
    const float* __restrict__ Dv,
    float* __restrict__ y_last)        // (B, DI)
{
    __shared__ float c_sh[NCH][DPER][N_];    // 16 KB
    __shared__ float dsum_sh[NCH][DPER];     // 256 B

    // bijective XCD swizzle: 2048 blocks = 8 * 256 -> batch-major per XCD
    const int bid = blockIdx.x;
    const int swz = (bid & 7) * 256 + (bid >> 3);
    const int b   = swz >> 6;                // 64 d-groups per batch
    const int d0  = (swz & 63) * DPER;

    const int wave = threadIdx.x >> 6;
    const int lane = threadIdx.x & 63;

    float Arow[DPER];
#pragma unroll
    for (int j = 0; j < DPER; j++)
        Arow[j] = -__expf(A_log[(size_t)(d0 + j) * N_ + lane]);

    const size_t rowBase = (size_t)b * L_;
    const float* dptr = delta + rowBase * DI_ + d0;
    const float* uptr = u     + rowBase * DI_ + d0;
    const float* bptr = dbc   + rowBase * 144 + R_ + lane;

#pragma unroll
    for (int ci = 0; ci < 2; ci++) {
        const int cc = wave + ci * 4;
        const int t0 = cc * CHT;

        float hs[DPER] = {0.f, 0.f, 0.f, 0.f, 0.f, 0.f, 0.f, 0.f};
        float dsm[DPER] = {0.f, 0.f, 0.f, 0.f, 0.f, 0.f, 0.f, 0.f};

        float4 dva = *(const float4*)(dptr + (size_t)t0 * DI_);
        float4 dvb = *(const float4*)(dptr + (size_t)t0 * DI_ + 4);
        float4 uva = *(const float4*)(uptr + (size_t)t0 * DI_);
        float4 uvb = *(const float4*)(uptr + (size_t)t0 * DI_ + 4);
        float  Bt  = bptr[(size_t)t0 * 144];

        for (int t = 0; t < CHT; t++) {
            const int tn = t0 + ((t + 1 < CHT) ? t + 1 : t);
            const float4 dna = *(const float4*)(dptr + (size_t)tn * DI_);
            const float4 dnb = *(const float4*)(dptr + (size_t)tn * DI_ + 4);
            const float4 una = *(const float4*)(uptr + (size_t)tn * DI_);
            const float4 unb = *(const float4*)(uptr + (size_t)tn * DI_ + 4);
            const float  Bn  = bptr[(size_t)tn * 144];

#define SSTEP(j, DD, UU) { \
            float e = __expf((DD) * Arow[j]); \
            hs[j] = fmaf(e, hs[j], (DD) * (UU) * Bt); \
            dsm[j] += (DD); }
            SSTEP(0, dva.x, uva.x)
            SSTEP(1, dva.y, uva.y)
            SSTEP(2, dva.z, uva.z)
            SSTEP(3, dva.w, uva.w)
            SSTEP(4, dvb.x, uvb.x)
            SSTEP(5, dvb.y, uvb.y)
            SSTEP(6, dvb.z, uvb.z)
            SSTEP(7, dvb.w, uvb.w)
#undef SSTEP
            dva = dna; dvb = dnb; uva = una; uvb = unb; Bt = Bn;
        }

#pragma unroll
        for (int j = 0; j < DPER; j++)
            c_sh[cc][j][lane] = hs[j];
        if (lane == 0) {
#pragma unroll
            for (int j = 0; j < DPER; j++)
                dsum_sh[cc][j] = dsm[j];
        }
    }
    __syncthreads();

    // combine: wave w handles d-offsets j = 2w, 2w+1
    const float Ct = dbc[(rowBase + L_ - 1) * 144 + R_ + N_ + lane];
#pragma unroll
    for (int jj = 0; jj < 2; jj++) {
        const int j = wave * 2 + jj;
        const int d = d0 + j;
        const float Aj = -__expf(A_log[(size_t)d * N_ + lane]);  // reload (L2-hot)
        float h = 0.f;
#pragma unroll
        for (int k = 0; k < NCH; k++) {
            const float e = __expf(Aj * dsum_sh[k][j]);
            h = fmaf(e, h, c_sh[k][j][lane]);
        }
        float v = h * Ct;
#pragma unroll
        for (int m = 32; m > 0; m >>= 1) v += __shfl_xor(v, m, 64);
        if (lane == 0) {
            const float ul = u[(rowBase + L_ - 1) * DI_ + d];
            y_last[b * DI_ + d] = v + ul * Dv[d];
        }
    }
}

// ---------------------------------------------------------------------------
// Final: gate, out_proj, fc1+relu, fc2, softmax.  One block per batch row.
// ---------------------------------------------------------------------------
__global__ __launch_bounds__(256) void final_kernel(
    const float* __restrict__ y_last, const float* __restrict__ z_last,
    const float* __restrict__ out_w,  const float* __restrict__ out_b,
    const float* __restrict__ fc1_w,  const float* __restrict__ fc1_b,
    const float* __restrict__ fc2_w,  const float* __restrict__ fc2_b,
    float* __restrict__ out)
{
    __shared__ float yz[DI_];
    __shared__ float feat[H_];
    __shared__ float h1[64];
    __shared__ float lg[2];
    const int b = blockIdx.x, tid = threadIdx.x;

    for (int d = tid; d < DI_; d += 256) {
        float z = z_last[b * DI_ + d];
        float s = 1.f / (1.f + __expf(-z));
        yz[d] = y_last[b * DI_ + d] * z * s;
    }
    __syncthreads();

    {
        float acc = out_b[tid];
        const float* wr = out_w + (size_t)tid * DI_;
        for (int d = 0; d < DI_; d++) acc = fmaf(yz[d], wr[d], acc);
        feat[tid] = acc;
    }
    __syncthreads();

    if (tid < 64) {
        float acc = fc1_b[tid];
        const float* wr = fc1_w + tid * H_;
        for (int hh = 0; hh < H_; hh++) acc = fmaf(feat[hh], wr[hh], acc);
        h1[tid] = acc > 0.f ? acc : 0.f;
    }
    __syncthreads();

    if (tid < 2) {
        float acc = fc2_b[tid];
        const float* wr = fc2_w + tid * 64;
        for (int j = 0; j < 64; j++) acc = fmaf(h1[j], wr[j], acc);
        lg[tid] = acc;
    }
    __syncthreads();

    if (tid == 0) {
        float m = fmaxf(lg[0], lg[1]);
        float e0 = __expf(lg[0] - m), e1 = __expf(lg[1] - m);
        float s = e0 + e1;
        out[b * 2 + 0] = e0 / s;
        out[b * 2 + 1] = e1 / s;
    }
}

// ---------------------------------------------------------------------------
extern "C" void kernel_launch(void* const* d_in, const int* in_sizes, int n_in,
                              void* d_out, int out_size, void* d_ws, size_t ws_size,
                              hipStream_t stream)
{
    const float* x         = (const float*)d_in[0];
    const float* emb_w     = (const float*)d_in[1];
    const float* emb_b     = (const float*)d_in[2];
    const float* in_proj_w = (const float*)d_in[3];
    const float* in_proj_b = (const float*)d_in[4];
    const float* conv_w    = (const float*)d_in[5];
    const float* conv_b    = (const float*)d_in[6];
    const float* x_proj_w  = (const float*)d_in[7];
    const float* dt_proj_w = (const float*)d_in[8];
    const float* dt_proj_b = (const float*)d_in[9];
    const float* A_log     = (const float*)d_in[10];
    const float* Dv        = (const float*)d_in[11];
    const float* out_w     = (const float*)d_in[12];
    const float* out_b     = (const float*)d_in[13];
    const float* fc1_w     = (const float*)d_in[14];
    const float* fc1_b     = (const float*)d_in[15];
    const float* fc2_w     = (const float*)d_in[16];
    const float* fc2_b     = (const float*)d_in[17];
    float* out = (float*)d_out;

    // workspace layout (floats)
    float* ws    = (float*)d_ws;
    float* hbuf  = ws;                      // 8192*256   = 2,097,152
    float* u_pre = hbuf  + 2097152;         // 8192*512   = 4,194,304
    float* ubuf  = u_pre + 4194304;         // 8192*512   = 4,194,304
    float* dbc   = ubuf  + 4194304;         // 8192*144   = 1,179,648
    float* delta = dbc   + 1179648;         // 8192*512   = 4,194,304
    float* zlast = delta + 4194304;         // 32*512
    float* ylast = zlast + B_ * DI_;        // 32*512

    dim3 blk(256);
    const int MBL = B_ * L_;  // 8192

    // 1. emb: h = x @ emb_w^T + emb_b           (8192,20)x(256,20)
    gemm_nt<0><<<dim3(H_ / BN, MBL / BM), blk, 0, stream>>>(
        x, F_, emb_w, F_, emb_b, hbuf, H_, MBL, H_, F_);

    // 2. in_proj (u half): u_pre = h @ Wu^T + bu (8192,256)x(512,256)
    gemm_nt<0><<<dim3(DI_ / BN, MBL / BM), blk, 0, stream>>>(
        hbuf, H_, in_proj_w, H_, in_proj_b, u_pre, DI_, MBL, DI_, H_);

    // 3. z at t = L-1 only: (32,256)x(512,256)
    gemm_nt<0><<<dim3(DI_ / BN, 1), blk, 0, stream>>>(
        hbuf + (L_ - 1) * H_, L_ * H_, in_proj_w + DI_ * H_, H_,
        in_proj_b + DI_, zlast, DI_, B_, DI_, H_);

    // 4. depthwise conv + SiLU
    conv_silu_kernel<<<(B_ * L_ * DI_) / 256, blk, 0, stream>>>(
        u_pre, conv_w, conv_b, ubuf);

    // 5. x_proj: dbc = u @ x_proj_w^T           (8192,512)x(144,512)
    gemm_nt<0><<<dim3(3, MBL / BM), blk, 0, stream>>>(
        ubuf, DI_, x_proj_w, DI_, nullptr, dbc, 144, MBL, 144, DI_);

    // 6. dt_proj + softplus: delta              (8192,16)x(512,16)
    gemm_nt<1><<<dim3(DI_ / BN, MBL / BM), blk, 0, stream>>>(
        dbc, 144, dt_proj_w, R_, dt_proj_b, delta, DI_, MBL, DI_, R_);

    // 7. chunked selective scan (fused combine; y only at last t)
    scan_chunk_kernel<<<B_ * (DI_ / DPER), blk, 0, stream>>>(
        delta, ubuf, dbc, A_log, Dv, ylast);

    // 8. gate + out_proj + fc1 + fc2 + softmax
    final_kernel<<<B_, blk, 0, stream>>>(
        ylast, zlast, out_w, out_b, fc1_w, fc1_b, fc2_w, fc2_b, out);
}

// Round 4
// 202.610 us; speedup vs baseline: 1.8242x; 1.5075x over previous
//
#include <hip/hip_runtime.h>
#include <hip/hip_bf16.h>
#include <math.h>

#define B_  32
#define L_  256
#define F_  20
#define H_  256
#define DI_ 512
#define N_  64
#define R_  16
#define KC_ 4
#define DS_ 192   // padded dbc row stride ([0:16)=dt [16:80)=B [80:144)=C [144:192)=pad)
#define NXP 192   // padded x_proj output rows

typedef __attribute__((ext_vector_type(8))) __bf16 bf16x8;
typedef __attribute__((ext_vector_type(4))) float f32x4;

__device__ __forceinline__ unsigned short f2bf(float f) {
    union { float f; unsigned u; } x; x.f = f;
    unsigned r = x.u + 0x7fff + ((x.u >> 16) & 1);   // RN-even (finite vals)
    return (unsigned short)(r >> 16);
}

// ---------------------------------------------------------------------------
// fp32 GEMM (NT), generic.  ACT: 0 none, 1 softplus.
// ---------------------------------------------------------------------------
#define BM  64
#define BN  64
#define BKT 16

template<int ACT>
__global__ __launch_bounds__(256) void gemm_nt(
    const float* __restrict__ A, int lda,
    const float* __restrict__ W, int ldw,
    const float* __restrict__ bias,
    float* __restrict__ C, int ldc,
    int M, int N, int K)
{
    __shared__ float As[BKT][BM + 4];
    __shared__ float Bs[BKT][BN + 4];
    const int tid = threadIdx.x;
    const int tx = tid & 15, ty = tid >> 4;
    const int m0 = blockIdx.y * BM;
    const int n0 = blockIdx.x * BN;
    float c[4][4] = {};

    for (int k0 = 0; k0 < K; k0 += BKT) {
#pragma unroll
        for (int i = 0; i < 4; i++) {
            int idx = tid + i * 256;
            int row = idx >> 4, kk = idx & 15;
            int m = m0 + row, k = k0 + kk;
            As[kk][row] = (m < M && k < K) ? A[(size_t)m * lda + k] : 0.f;
            int n = n0 + row;
            Bs[kk][row] = (n < N && k < K) ? W[(size_t)n * ldw + k] : 0.f;
        }
        __syncthreads();
#pragma unroll
        for (int kk = 0; kk < BKT; kk++) {
            const float4 av = *(const float4*)&As[kk][ty * 4];
            const float4 bv = *(const float4*)&Bs[kk][tx * 4];
            const float a0 = av.x, a1 = av.y, a2 = av.z, a3 = av.w;
            const float b0 = bv.x, b1 = bv.y, b2 = bv.z, b3 = bv.w;
            c[0][0] = fmaf(a0, b0, c[0][0]); c[0][1] = fmaf(a0, b1, c[0][1]);
            c[0][2] = fmaf(a0, b2, c[0][2]); c[0][3] = fmaf(a0, b3, c[0][3]);
            c[1][0] = fmaf(a1, b0, c[1][0]); c[1][1] = fmaf(a1, b1, c[1][1]);
            c[1][2] = fmaf(a1, b2, c[1][2]); c[1][3] = fmaf(a1, b3, c[1][3]);
            c[2][0] = fmaf(a2, b0, c[2][0]); c[2][1] = fmaf(a2, b1, c[2][1]);
            c[2][2] = fmaf(a2, b2, c[2][2]); c[2][3] = fmaf(a2, b3, c[2][3]);
            c[3][0] = fmaf(a3, b0, c[3][0]); c[3][1] = fmaf(a3, b1, c[3][1]);
            c[3][2] = fmaf(a3, b2, c[3][2]); c[3][3] = fmaf(a3, b3, c[3][3]);
        }
        __syncthreads();
    }

#pragma unroll
    for (int i = 0; i < 4; i++) {
        int m = m0 + ty * 4 + i;
        if (m >= M) continue;
#pragma unroll
        for (int j = 0; j < 4; j++) {
            int n = n0 + tx * 4 + j;
            if (n >= N) continue;
            float v = c[i][j];
            if (bias) v += bias[n];
            if (ACT == 1) v = (v > 20.f) ? v : log1pf(__expf(v));
            C[(size_t)m * ldc + n] = v;
        }
    }
}

// ---------------------------------------------------------------------------
// emb GEMM (fp32 compute): h = x @ emb_w^T + emb_b.  Writes bf16 h for the
// MFMA in_proj, and fp32 rows only at t = L-1 (for the z gate).
// ---------------------------------------------------------------------------
__global__ __launch_bounds__(256) void gemm_emb(
    const float* __restrict__ A,      // (B*L, F)
    const float* __restrict__ W,      // (H, F)
    const float* __restrict__ bias,
    unsigned short* __restrict__ Hb,  // (B*L, H) bf16
    float* __restrict__ hlast)        // (B, H) fp32
{
    __shared__ float As[BKT][BM + 4];
    __shared__ float Bs[BKT][BN + 4];
    const int tid = threadIdx.x;
    const int tx = tid & 15, ty = tid >> 4;
    const int m0 = blockIdx.y * BM;
    const int n0 = blockIdx.x * BN;
    float c[4][4] = {};

    for (int k0 = 0; k0 < F_; k0 += BKT) {
#pragma unroll
        for (int i = 0; i < 4; i++) {
            int idx = tid + i * 256;
            int row = idx >> 4, kk = idx & 15;
            int k = k0 + kk;
            As[kk][row] = (k < F_) ? A[(size_t)(m0 + row) * F_ + k] : 0.f;
            Bs[kk][row] = (k < F_) ? W[(size_t)(n0 + row) * F_ + k] : 0.f;
        }
        __syncthreads();
#pragma unroll
        for (int kk = 0; kk < BKT; kk++) {
            const float4 av = *(const float4*)&As[kk][ty * 4];
            const float4 bv = *(const float4*)&Bs[kk][tx * 4];
            const float a0 = av.x, a1 = av.y, a2 = av.z, a3 = av.w;
            const float b0 = bv.x, b1 = bv.y, b2 = bv.z, b3 = bv.w;
            c[0][0] = fmaf(a0, b0, c[0][0]); c[0][1] = fmaf(a0, b1, c[0][1]);
            c[0][2] = fmaf(a0, b2, c[0][2]); c[0][3] = fmaf(a0, b3, c[0][3]);
            c[1][0] = fmaf(a1, b0, c[1][0]); c[1][1] = fmaf(a1, b1, c[1][1]);
            c[1][2] = fmaf(a1, b2, c[1][2]); c[1][3] = fmaf(a1, b3, c[1][3]);
            c[2][0] = fmaf(a2, b0, c[2][0]); c[2][1] = fmaf(a2, b1, c[2][1]);
            c[2][2] = fmaf(a2, b2, c[2][2]); c[2][3] = fmaf(a2, b3, c[2][3]);
            c[3][0] = fmaf(a3, b0, c[3][0]); c[3][1] = fmaf(a3, b1, c[3][1]);
            c[3][2] = fmaf(a3, b2, c[3][2]); c[3][3] = fmaf(a3, b3, c[3][3]);
        }
        __syncthreads();
    }

#pragma unroll
    for (int i = 0; i < 4; i++) {
        int m = m0 + ty * 4 + i;
#pragma unroll
        for (int j = 0; j < 4; j++) {
            int n = n0 + tx * 4 + j;
            float v = c[i][j] + bias[n];
            Hb[(size_t)m * H_ + n] = f2bf(v);
            if ((m & (L_ - 1)) == L_ - 1)
                hlast[(m >> 8) * H_ + n] = v;
        }
    }
}

// ---------------------------------------------------------------------------
// weight conversion: in_proj u-half (512x256) -> bf16; x_proj (144x512) ->
// bf16 padded to 192 rows (zeros).
// ---------------------------------------------------------------------------
__global__ __launch_bounds__(256) void convert_weights(
    const float* __restrict__ in_proj_w,
    const float* __restrict__ x_proj_w,
    unsigned short* __restrict__ wu,
    unsigned short* __restrict__ wx)
{
    int i = blockIdx.x * 256 + threadIdx.x;
    const int n1 = DI_ * H_;        // 131072
    if (i < n1) { wu[i] = f2bf(in_proj_w[i]); return; }
    i -= n1;
    // i in [0, NXP*DI_)
    int r = i / DI_;
    wx[i] = (r < R_ + 2 * N_) ? f2bf(x_proj_w[i]) : (unsigned short)0;
}

// ---------------------------------------------------------------------------
// bf16 MFMA GEMM (NT): C[m,n] = sum_k A[m,k] * W[n,k] (+bias), fp32 out.
// No LDS: operands are L2-resident.  Block = 4 waves, tile 128 x (16*NREP).
// Wave tile 32 x (16*NREP): 2 m-frags x NREP n-frags of 16x16x32 MFMA.
// Frag layout (gfx950 16x16x32): A row=lane&15, k=(lane>>4)*8+i ;
// B col=lane&15, same k ; D col=lane&15, row=(lane>>4)*4+reg.
// Requires M%128==0, N%(16*NREP)==0, K%32==0.
// ---------------------------------------------------------------------------
template<int NREP>
__global__ __launch_bounds__(256) void gemm_bf16(
    const unsigned short* __restrict__ Abf,  // M x K
    const unsigned short* __restrict__ Wbf,  // N x K
    const float* __restrict__ bias,          // len N or nullptr
    float* __restrict__ C, int ldc,
    int M, int N, int K)
{
    const int wave = threadIdx.x >> 6, lane = threadIdx.x & 63;
    const int lm = lane & 15, kg = lane >> 4;
    const int m0 = blockIdx.y * 128 + wave * 32;
    const int n0 = blockIdx.x * (16 * NREP);

    const unsigned short* a0p = Abf + (size_t)(m0 + lm) * K + kg * 8;
    const unsigned short* a1p = a0p + (size_t)16 * K;
    const unsigned short* bp[NREP];
#pragma unroll
    for (int j = 0; j < NREP; j++)
        bp[j] = Wbf + (size_t)(n0 + j * 16 + lm) * K + kg * 8;

    f32x4 acc[2][NREP];
#pragma unroll
    for (int i = 0; i < 2; i++)
#pragma unroll
        for (int j = 0; j < NREP; j++)
            acc[i][j] = (f32x4){0.f, 0.f, 0.f, 0.f};

    for (int k0 = 0; k0 < K; k0 += 32) {
        bf16x8 a0 = *(const bf16x8*)(a0p + k0);
        bf16x8 a1 = *(const bf16x8*)(a1p + k0);
#pragma unroll
        for (int j = 0; j < NREP; j++) {
            bf16x8 b = *(const bf16x8*)(bp[j] + k0);
            acc[0][j] = __builtin_amdgcn_mfma_f32_16x16x32_bf16(a0, b, acc[0][j], 0, 0, 0);
            acc[1][j] = __builtin_amdgcn_mfma_f32_16x16x32_bf16(a1, b, acc[1][j], 0, 0, 0);
        }
    }

#pragma unroll
    for (int i = 0; i < 2; i++) {
        const int mbase = m0 + i * 16 + kg * 4;
#pragma unroll
        for (int j = 0; j < NREP; j++) {
            const int n = n0 + j * 16 + lm;
            const float bj = bias ? bias[n] : 0.f;
#pragma unroll
            for (int r = 0; r < 4; r++)
                C[(size_t)(mbase + r) * ldc + n] = acc[i][j][r] + bj;
        }
    }
}

// ---------------------------------------------------------------------------
// Depthwise causal conv (K=4) + SiLU, 4 d's per thread.  Writes fp32 + bf16.
// ---------------------------------------------------------------------------
__global__ __launch_bounds__(256) void conv_silu_kernel(
    const float* __restrict__ u_pre,
    const float* __restrict__ conv_w,
    const float* __restrict__ conv_b,
    float* __restrict__ u,
    unsigned short* __restrict__ u_bf)
{
    const int id = blockIdx.x * 256 + threadIdx.x;
    if (id >= B_ * L_ * DI_ / 4) return;
    const int d0 = (id % (DI_ / 4)) * 4;
    const int bl = id / (DI_ / 4);
    const int t  = bl % L_;

    float w_[4][4];
#pragma unroll
    for (int dd = 0; dd < 4; dd++) {
        const float4 wv = *(const float4*)&conv_w[(d0 + dd) * KC_];
        w_[dd][0] = wv.x; w_[dd][1] = wv.y; w_[dd][2] = wv.z; w_[dd][3] = wv.w;
    }
    float a0 = conv_b[d0], a1 = conv_b[d0 + 1], a2 = conv_b[d0 + 2], a3 = conv_b[d0 + 3];
#pragma unroll
    for (int k = 0; k < KC_; k++) {
        const int tt = t + k - (KC_ - 1);
        if (tt >= 0) {
            const float4 v = *(const float4*)&u_pre[(size_t)(bl + k - (KC_ - 1)) * DI_ + d0];
            a0 = fmaf(v.x, w_[0][k], a0);
            a1 = fmaf(v.y, w_[1][k], a1);
            a2 = fmaf(v.z, w_[2][k], a2);
            a3 = fmaf(v.w, w_[3][k], a3);
        }
    }
    a0 *= 1.f / (1.f + __expf(-a0));
    a1 *= 1.f / (1.f + __expf(-a1));
    a2 *= 1.f / (1.f + __expf(-a2));
    a3 *= 1.f / (1.f + __expf(-a3));
    float4 o = {a0, a1, a2, a3};
    *(float4*)&u[(size_t)bl * DI_ + d0] = o;
    uint2 p;
    p.x = (unsigned)f2bf(a0) | ((unsigned)f2bf(a1) << 16);
    p.y = (unsigned)f2bf(a2) | ((unsigned)f2bf(a3) << 16);
    *(uint2*)&u_bf[(size_t)bl * DI_ + d0] = p;
}

// ---------------------------------------------------------------------------
// Chunked selective scan (unchanged except dbc stride 192).
// ---------------------------------------------------------------------------
#define DPER 8
#define NCH  8
#define CHT  32

__global__ __launch_bounds__(256) void scan_chunk_kernel(
    const float* __restrict__ delta,
    const float* __restrict__ u,
    const float* __restrict__ dbc,
    const float* __restrict__ A_log,
    const float* __restrict__ Dv,
    float* __restrict__ y_last)
{
    __shared__ float c_sh[NCH][DPER][N_];
    __shared__ float dsum_sh[NCH][DPER];

    const int bid = blockIdx.x;
    const int swz = (bid & 7) * 256 + (bid >> 3);
    const int b   = swz >> 6;
    const int d0  = (swz & 63) * DPER;

    const int wave = threadIdx.x >> 6;
    const int lane = threadIdx.x & 63;

    float Arow[DPER];
#pragma unroll
    for (int j = 0; j < DPER; j++)
        Arow[j] = -__expf(A_log[(size_t)(d0 + j) * N_ + lane]);

    const size_t rowBase = (size_t)b * L_;
    const float* dptr = delta + rowBase * DI_ + d0;
    const float* uptr = u     + rowBase * DI_ + d0;
    const float* bptr = dbc   + rowBase * DS_ + R_ + lane;

#pragma unroll
    for (int ci = 0; ci < 2; ci++) {
        const int cc = wave + ci * 4;
        const int t0 = cc * CHT;

        float hs[DPER]  = {0.f, 0.f, 0.f, 0.f, 0.f, 0.f, 0.f, 0.f};
        float dsm[DPER] = {0.f, 0.f, 0.f, 0.f, 0.f, 0.f, 0.f, 0.f};

        float4 dva = *(const float4*)(dptr + (size_t)t0 * DI_);
        float4 dvb = *(const float4*)(dptr + (size_t)t0 * DI_ + 4);
        float4 uva = *(const float4*)(uptr + (size_t)t0 * DI_);
        float4 uvb = *(const float4*)(uptr + (size_t)t0 * DI_ + 4);
        float  Bt  = bptr[(size_t)t0 * DS_];

        for (int t = 0; t < CHT; t++) {
            const int tn = t0 + ((t + 1 < CHT) ? t + 1 : t);
            const float4 dna = *(const float4*)(dptr + (size_t)tn * DI_);
            const float4 dnb = *(const float4*)(dptr + (size_t)tn * DI_ + 4);
            const float4 una = *(const float4*)(uptr + (size_t)tn * DI_);
            const float4 unb = *(const float4*)(uptr + (size_t)tn * DI_ + 4);
            const float  Bn  = bptr[(size_t)tn * DS_];

#define SSTEP(j, DD, UU) { \
            float e = __expf((DD) * Arow[j]); \
            hs[j] = fmaf(e, hs[j], (DD) * (UU) * Bt); \
            dsm[j] += (DD); }
            SSTEP(0, dva.x, uva.x)
            SSTEP(1, dva.y, uva.y)
            SSTEP(2, dva.z, uva.z)
            SSTEP(3, dva.w, uva.w)
            SSTEP(4, dvb.x, uvb.x)
            SSTEP(5, dvb.y, uvb.y)
            SSTEP(6, dvb.z, uvb.z)
            SSTEP(7, dvb.w, uvb.w)
#undef SSTEP
            dva = dna; dvb = dnb; uva = una; uvb = unb; Bt = Bn;
        }

#pragma unroll
        for (int j = 0; j < DPER; j++)
            c_sh[cc][j][lane] = hs[j];
        if (lane == 0) {
#pragma unroll
            for (int j = 0; j < DPER; j++)
                dsum_sh[cc][j] = dsm[j];
        }
    }
    __syncthreads();

    const float Ct = dbc[(rowBase + L_ - 1) * DS_ + R_ + N_ + lane];
#pragma unroll
    for (int jj = 0; jj < 2; jj++) {
        const int j = wave * 2 + jj;
        const int d = d0 + j;
        const float Aj = -__expf(A_log[(size_t)d * N_ + lane]);
        float h = 0.f;
#pragma unroll
        for (int k = 0; k < NCH; k++) {
            const float e = __expf(Aj * dsum_sh[k][j]);
            h = fmaf(e, h, c_sh[k][j][lane]);
        }
        float v = h * Ct;
#pragma unroll
        for (int m = 32; m > 0; m >>= 1) v += __shfl_xor(v, m, 64);
        if (lane == 0) {
            const float ul = u[(rowBase + L_ - 1) * DI_ + d];
            y_last[b * DI_ + d] = v + ul * Dv[d];
        }
    }
}

// ---------------------------------------------------------------------------
// Final: z-gate GEMV + gate + out_proj + fc1 + fc2 + softmax.  1 block / b.
// ---------------------------------------------------------------------------
__global__ __launch_bounds__(256) void final_kernel(
    const float* __restrict__ y_last, const float* __restrict__ hlast,
    const float* __restrict__ in_proj_w, const float* __restrict__ in_proj_b,
    const float* __restrict__ out_w,  const float* __restrict__ out_b,
    const float* __restrict__ fc1_w,  const float* __restrict__ fc1_b,
    const float* __restrict__ fc2_w,  const float* __restrict__ fc2_b,
    float* __restrict__ out)
{
    __shared__ float hl[H_];
    __shared__ float yz[DI_];
    __shared__ float feat[H_];
    __shared__ float h1[64];
    __shared__ float lg[2];
    const int b = blockIdx.x, tid = threadIdx.x;

    hl[tid] = hlast[b * H_ + tid];
    __syncthreads();

    for (int d = tid; d < DI_; d += 256) {
        const float* wr = in_proj_w + (size_t)(DI_ + d) * H_;
        float z = in_proj_b[DI_ + d];
        for (int h = 0; h < H_; h++) z = fmaf(hl[h], wr[h], z);
        float s = 1.f / (1.f + __expf(-z));
        yz[d] = y_last[b * DI_ + d] * z * s;
    }
    __syncthreads();

    {
        float acc = out_b[tid];
        const float* wr = out_w + (size_t)tid * DI_;
        for (int d = 0; d < DI_; d++) acc = fmaf(yz[d], wr[d], acc);
        feat[tid] = acc;
    }
    __syncthreads();

    if (tid < 64) {
        float acc = fc1_b[tid];
        const float* wr = fc1_w + tid * H_;
        for (int hh = 0; hh < H_; hh++) acc = fmaf(feat[hh], wr[hh], acc);
        h1[tid] = acc > 0.f ? acc : 0.f;
    }
    __syncthreads();

    if (tid < 2) {
        float acc = fc2_b[tid];
        const float* wr = fc2_w + tid * 64;
        for (int j = 0; j < 64; j++) acc = fmaf(h1[j], wr[j], acc);
        lg[tid] = acc;
    }
    __syncthreads();

    if (tid == 0) {
        float m = fmaxf(lg[0], lg[1]);
        float e0 = __expf(lg[0] - m), e1 = __expf(lg[1] - m);
        float s = e0 + e1;
        out[b * 2 + 0] = e0 / s;
        out[b * 2 + 1] = e1 / s;
    }
}

// ---------------------------------------------------------------------------
extern "C" void kernel_launch(void* const* d_in, const int* in_sizes, int n_in,
                              void* d_out, int out_size, void* d_ws, size_t ws_size,
                              hipStream_t stream)
{
    const float* x         = (const float*)d_in[0];
    const float* emb_w     = (const float*)d_in[1];
    const float* emb_b     = (const float*)d_in[2];
    const float* in_proj_w = (const float*)d_in[3];
    const float* in_proj_b = (const float*)d_in[4];
    const float* conv_w    = (const float*)d_in[5];
    const float* conv_b    = (const float*)d_in[6];
    const float* x_proj_w  = (const float*)d_in[7];
    const float* dt_proj_w = (const float*)d_in[8];
    const float* dt_proj_b = (const float*)d_in[9];
    const float* A_log     = (const float*)d_in[10];
    const float* Dv        = (const float*)d_in[11];
    const float* out_w     = (const float*)d_in[12];
    const float* out_b     = (const float*)d_in[13];
    const float* fc1_w     = (const float*)d_in[14];
    const float* fc1_b     = (const float*)d_in[15];
    const float* fc2_w     = (const float*)d_in[16];
    const float* fc2_b     = (const float*)d_in[17];
    float* out = (float*)d_out;

    // workspace layout (float units, all 16B-aligned)
    float* ws = (float*)d_ws;
    unsigned short* h_bf  = (unsigned short*)ws;            // 8192*256 bf16  = 1,048,576 fl
    float* hlast          = ws + 1048576;                   // 32*256         =     8,192
    unsigned short* wu_bf = (unsigned short*)(ws + 1056768);// 512*256 bf16   =    65,536 fl
    unsigned short* wx_bf = (unsigned short*)(ws + 1122304);// 192*512 bf16   =    49,152 fl
    float* u_pre          = ws + 1171456;                   // 8192*512       = 4,194,304 (aliased by delta)
    float* u              = u_pre + 4194304;                // 8192*512       = 4,194,304
    unsigned short* u_bf  = (unsigned short*)(u + 4194304); // 8192*512 bf16  = 2,097,152 fl
    float* dbc            = u + 4194304 + 2097152;          // 8192*192       = 1,572,864
    float* ylast          = dbc + 1572864;                  // 32*512
    float* delta          = u_pre;                          // alias (u_pre dead after conv)

    dim3 blk(256);
    const int MBL = B_ * L_;  // 8192

    // 0. weight conversion (bf16)
    convert_weights<<<(DI_ * H_ + NXP * DI_) / 256, blk, 0, stream>>>(
        in_proj_w, x_proj_w, wu_bf, wx_bf);

    // 1. emb: h = x @ emb_w^T + emb_b  -> bf16 h (+ fp32 last-t rows)
    gemm_emb<<<dim3(H_ / BN, MBL / BM), blk, 0, stream>>>(
        x, emb_w, emb_b, h_bf, hlast);

    // 2. in_proj (u half), bf16 MFMA: (8192,256)x(512,256) -> u_pre fp32
    gemm_bf16<4><<<dim3(DI_ / 64, MBL / 128), blk, 0, stream>>>(
        h_bf, wu_bf, in_proj_b, u_pre, DI_, MBL, DI_, H_);

    // 3. depthwise conv + SiLU -> u fp32 + bf16
    conv_silu_kernel<<<(B_ * L_ * DI_ / 4) / 256, blk, 0, stream>>>(
        u_pre, conv_w, conv_b, u, u_bf);

    // 4. x_proj, bf16 MFMA: (8192,512)x(192,512) -> dbc fp32 (stride 192)
    gemm_bf16<4><<<dim3(NXP / 64, MBL / 128), blk, 0, stream>>>(
        u_bf, wx_bf, nullptr, dbc, DS_, MBL, NXP, DI_);

    // 5. dt_proj + softplus (fp32): (8192,16)x(512,16) -> delta
    gemm_nt<1><<<dim3(DI_ / BN, MBL / BM), blk, 0, stream>>>(
        dbc, DS_, dt_proj_w, R_, dt_proj_b, delta, DI_, MBL, DI_, R_);

    // 6. chunked selective scan
    scan_chunk_kernel<<<B_ * (DI_ / DPER), blk, 0, stream>>>(
        delta, u, dbc, A_log, Dv, ylast);

    // 7. z-gate + out_proj + fc1 + fc2 + softmax
    final_kernel<<<B_, blk, 0, stream>>>(
        ylast, hlast, in_proj_w, in_proj_b, out_w, out_b,
        fc1_w, fc1_b, fc2_w, fc2_b, out);
}